// Round 1
// baseline (607.485 us; speedup 1.0000x reference)
//
#include <hip/hip_runtime.h>

// ---------------------------------------------------------------------------
// MambaLayer on MI355X (gfx950).
// Pipeline (all f16 MFMA with fp32 accumulate; scan/elementwise in fp32):
//   1. convert x -> f16; transpose-convert W_in, W_out -> N-major f16 (B^T form)
//   2. GEMM1: xr = x @ W_in        (16384x1024 @ 1024x4096), f16 out
//   3. conv(3, depthwise, pad 1) + SiLU -> xc (f16)
//   4. bc_gemm: BtCt = xc @ [W_B|W_C]  (N=32, fp32 out)
//   5. chunk-parallel scan -> ys (fp32, 16384)
//   6. fuse_y: y = (ys + xc*D) * silu(res) -> overwrite xc buffer (f16)
//   7. GEMM2: out = y @ W_out      (16384x2048 @ 2048x1024), fp32 out
// ---------------------------------------------------------------------------

typedef _Float16 half8 __attribute__((ext_vector_type(8)));
typedef float floatx4 __attribute__((ext_vector_type(4)));

#define D_MODEL 1024
#define D_INNER 2048
#define SEQ     4096
#define NBATCH  4
#define NROWS   (NBATCH * SEQ)        // 16384

__device__ __forceinline__ void async16(_Float16* lds, const _Float16* g) {
    // global -> LDS direct copy, 16B per lane; LDS dest = wave-uniform base + lane*16
    __builtin_amdgcn_global_load_lds((const __attribute__((address_space(1))) void*)g,
                                     (__attribute__((address_space(3))) void*)lds, 16, 0, 0);
}

__device__ __forceinline__ float siluf(float x) {
    return x / (1.f + __expf(-x));
}

// --------------------------- conversion kernels ----------------------------

__global__ __launch_bounds__(256) void convert_f32_f16(const float* __restrict__ src,
                                                       _Float16* __restrict__ dst) {
    size_t idx = ((size_t)blockIdx.x * 256 + threadIdx.x) * 8;
    float4 a = *(const float4*)(src + idx);
    float4 b = *(const float4*)(src + idx + 4);
    half8 o = {(_Float16)a.x, (_Float16)a.y, (_Float16)a.z, (_Float16)a.w,
               (_Float16)b.x, (_Float16)b.y, (_Float16)b.z, (_Float16)b.w};
    *(half8*)(dst + idx) = o;
}

// src: K x N fp32 (row-major), dst: N x K f16 (row-major)  [i.e. B^T]
__global__ __launch_bounds__(256) void transpose_to_f16(const float* __restrict__ src,
                                                        _Float16* __restrict__ dst,
                                                        int K, int N) {
    __shared__ float tile[32][33];
    int n0 = blockIdx.x * 32, k0 = blockIdx.y * 32;
    int x = threadIdx.x, y = threadIdx.y;   // 32 x 8
#pragma unroll
    for (int r = 0; r < 32; r += 8)
        tile[y + r][x] = src[(size_t)(k0 + y + r) * N + (n0 + x)];
    __syncthreads();
#pragma unroll
    for (int r = 0; r < 32; r += 8)
        dst[(size_t)(n0 + y + r) * K + (k0 + x)] = (_Float16)tile[x][y + r];
}

// WBCT[n][k], n<16 -> W_B[:,n], n>=16 -> W_C[:,n-16]; shape 32 x 2048 f16
__global__ __launch_bounds__(256) void convert_wbct(const float* __restrict__ WB,
                                                    const float* __restrict__ WC,
                                                    _Float16* __restrict__ WBCT) {
    int idx = blockIdx.x * 256 + threadIdx.x;   // 0 .. 65535
    int n = idx >> 11, k = idx & 2047;
    float v = (n < 16) ? WB[k * 16 + n] : WC[k * 16 + (n - 16)];
    WBCT[idx] = (_Float16)v;
}

// ------------------------------- main GEMM ---------------------------------
// C(MxN) = A(MxK) * B(KxN), with B given as BT (NxK row-major). All f16 in,
// fp32 accumulate. 128x128 block tile, BK=32, 4 waves in 2x2 of 64x64.
template <typename OutT>
__global__ __launch_bounds__(256) void gemm_tn(const _Float16* __restrict__ A,
                                               const _Float16* __restrict__ BT,
                                               OutT* __restrict__ C,
                                               int M, int N, int K) {
    __shared__ __align__(16) _Float16 As[128 * 32];
    __shared__ __align__(16) _Float16 Bs[128 * 32];
    const int tid = threadIdx.x;
    const int wid = tid >> 6, lane = tid & 63;
    const int row0 = blockIdx.y * 128, col0 = blockIdx.x * 128;
    const int wm = (wid & 1) * 64, wn = (wid >> 1) * 64;

    floatx4 acc[4][4] = {};

    // staging: each wave owns 2 x 1KB regions of As and Bs (regions wid*2, wid*2+1)
    const int srow = lane >> 2;            // 0..15 row within region
    const int scol = (lane & 3) * 8;       // 0,8,16,24 (f16 elements)
    const size_t aOff0 = (size_t)(row0 + wid * 32 + srow) * K + scol;
    const size_t aOff1 = aOff0 + (size_t)16 * K;
    const size_t bOff0 = (size_t)(col0 + wid * 32 + srow) * K + scol;
    const size_t bOff1 = bOff0 + (size_t)16 * K;
    _Float16* ldsA = As + wid * 1024;      // 2 regions x 512 elements
    _Float16* ldsB = Bs + wid * 1024;

    const int fr = lane & 15, fc = (lane >> 4) * 8;

    for (int k0 = 0; k0 < K; k0 += 32) {
        __syncthreads();
        async16(ldsA,       A + aOff0 + k0);
        async16(ldsA + 512, A + aOff1 + k0);
        async16(ldsB,       BT + bOff0 + k0);
        async16(ldsB + 512, BT + bOff1 + k0);
        __syncthreads();
        half8 af[4], bf[4];
#pragma unroll
        for (int i = 0; i < 4; i++)
            af[i] = *(const half8*)(As + (wm + i * 16 + fr) * 32 + fc);
#pragma unroll
        for (int i = 0; i < 4; i++)
            bf[i] = *(const half8*)(Bs + (wn + i * 16 + fr) * 32 + fc);
#pragma unroll
        for (int i = 0; i < 4; i++)
#pragma unroll
            for (int j = 0; j < 4; j++)
                acc[i][j] = __builtin_amdgcn_mfma_f32_16x16x32_f16(af[i], bf[j], acc[i][j], 0, 0, 0);
    }

    // C/D layout: col = lane&15, row = (lane>>4)*4 + reg   [measured m89/m91]
    const int er = (lane >> 4) * 4, ec = lane & 15;
#pragma unroll
    for (int i = 0; i < 4; i++)
#pragma unroll
        for (int j = 0; j < 4; j++)
#pragma unroll
            for (int r = 0; r < 4; r++) {
                int row = row0 + wm + i * 16 + er + r;
                int col = col0 + wn + j * 16 + ec;
                C[(size_t)row * N + col] = (OutT)acc[i][j][r];
            }
}

// ------------------------- skinny GEMM for Bt/Ct ---------------------------
// BtCt(M x 32) = xc(M x 2048) @ [W_B | W_C]; BT = WBCT (32 x 2048 f16).
__global__ __launch_bounds__(256) void bc_gemm(const _Float16* __restrict__ A,
                                               const _Float16* __restrict__ BT,
                                               float* __restrict__ C) {
    const int K = D_INNER;
    __shared__ __align__(16) _Float16 As[64 * 64];
    __shared__ __align__(16) _Float16 Bs[32 * 64];
    const int tid = threadIdx.x, wid = tid >> 6, lane = tid & 63;
    const int row0 = blockIdx.x * 64;
    floatx4 acc[2] = {};

    const int srow = lane >> 3;            // 0..7
    const int scol = (lane & 7) * 8;       // 0..56
    const size_t aOff0 = (size_t)(row0 + wid * 16 + srow) * K + scol;
    const size_t aOff1 = aOff0 + (size_t)8 * K;
    const size_t bOff  = (size_t)(wid * 8 + srow) * K + scol;
    _Float16* ldsA = As + wid * 1024;
    _Float16* ldsB = Bs + wid * 512;
    const int fr = lane & 15, fc = (lane >> 4) * 8;

    for (int k0 = 0; k0 < K; k0 += 64) {
        __syncthreads();
        async16(ldsA,       A + aOff0 + k0);
        async16(ldsA + 512, A + aOff1 + k0);
        async16(ldsB,       BT + bOff + k0);
        __syncthreads();
#pragma unroll
        for (int s = 0; s < 2; s++) {
            half8 af = *(const half8*)(As + (wid * 16 + fr) * 64 + s * 32 + fc);
#pragma unroll
            for (int nj = 0; nj < 2; nj++) {
                half8 bf = *(const half8*)(Bs + (nj * 16 + fr) * 64 + s * 32 + fc);
                acc[nj] = __builtin_amdgcn_mfma_f32_16x16x32_f16(af, bf, acc[nj], 0, 0, 0);
            }
        }
    }
    const int er = (lane >> 4) * 4, ec = lane & 15;
#pragma unroll
    for (int nj = 0; nj < 2; nj++)
#pragma unroll
        for (int r = 0; r < 4; r++)
            C[(size_t)(row0 + wid * 16 + er + r) * 32 + nj * 16 + ec] = acc[nj][r];
}

// ----------------------------- conv + silu ---------------------------------
__global__ __launch_bounds__(256) void conv_silu(const _Float16* __restrict__ xr,
                                                 const float* __restrict__ cw,
                                                 const float* __restrict__ cb,
                                                 _Float16* __restrict__ xc) {
    int row = blockIdx.x;           // b*SEQ + l
    int l = row & (SEQ - 1);
    int i = threadIdx.x * 8;
    const _Float16* cur = xr + (size_t)row * 4096 + i;   // x_main = cols [0,2048)
    half8 c8 = *(const half8*)cur;
    half8 p8 = {}, n8 = {};
    if (l > 0)       p8 = *(const half8*)(cur - 4096);
    if (l < SEQ - 1) n8 = *(const half8*)(cur + 4096);
    half8 o;
#pragma unroll
    for (int j = 0; j < 8; j++) {
        int ii = i + j;
        float a = (float)p8[j] * cw[ii * 3] + (float)c8[j] * cw[ii * 3 + 1] +
                  (float)n8[j] * cw[ii * 3 + 2] + cb[ii];
        o[j] = (_Float16)siluf(a);
    }
    *(half8*)(xc + (size_t)row * D_INNER + i) = o;
}

// -------------------------------- scan -------------------------------------
// state[s] = state[s]*decay[s] + Bt[l,s];  ys[l] = sum_s state[s]*Ct[l,s]
// 3-phase chunked scan: 16 chunks x 256 steps per batch; thread = (chunk, s).
__global__ __launch_bounds__(256) void scan_kernel(const float* __restrict__ BtCt,
                                                   const float* __restrict__ A,
                                                   float* __restrict__ ys) {
    const int b = blockIdx.x, t = threadIdx.x;
    const int c = t >> 4, s = t & 15;
    const float decay = __expf(-log1pf(__expf(A[s])));
    const size_t base = (size_t)b * SEQ * 32;
    const int l0 = c * 256;

    float st = 0.f;
    for (int j = 0; j < 256; j++)
        st = st * decay + BtCt[base + (size_t)(l0 + j) * 32 + s];

    __shared__ float fin[16][16];
    __shared__ float carry[16][16];
    fin[c][s] = st;
    __syncthreads();
    if (t < 16) {                       // c==0, s==t
        float d256 = decay;
#pragma unroll
        for (int k = 0; k < 8; k++) d256 *= d256;   // decay^256
        float cy = 0.f;
        for (int cc = 0; cc < 16; cc++) {
            carry[cc][s] = cy;
            cy = cy * d256 + fin[cc][s];
        }
    }
    __syncthreads();

    st = carry[c][s];
    for (int j = 0; j < 256; j++) {
        size_t r = base + (size_t)(l0 + j) * 32;
        st = st * decay + BtCt[r + s];
        float y = st * BtCt[r + 16 + s];
        y += __shfl_xor(y, 1, 16);
        y += __shfl_xor(y, 2, 16);
        y += __shfl_xor(y, 4, 16);
        y += __shfl_xor(y, 8, 16);
        if (s == 0) ys[b * SEQ + l0 + j] = y;
    }
}

// ------------------------- fused elementwise y -----------------------------
// y = (ys + xc*D) * silu(res); overwrite xc in place (read-once elementwise).
__global__ __launch_bounds__(256) void fuse_y(const float* __restrict__ ys,
                                              const float* __restrict__ D,
                                              const _Float16* __restrict__ xr,
                                              _Float16* __restrict__ xc) {
    int row = blockIdx.x;
    int i = threadIdx.x * 8;
    float yv = ys[row];
    half8 x8 = *(const half8*)(xc + (size_t)row * D_INNER + i);
    half8 r8 = *(const half8*)(xr + (size_t)row * 4096 + 2048 + i);
    half8 o;
#pragma unroll
    for (int j = 0; j < 8; j++) {
        float y = yv + (float)x8[j] * D[i + j];
        o[j] = (_Float16)(y * siluf((float)r8[j]));
    }
    *(half8*)(xc + (size_t)row * D_INNER + i) = o;
}

// ------------------------------- launcher ----------------------------------
extern "C" void kernel_launch(void* const* d_in, const int* in_sizes, int n_in,
                              void* d_out, int out_size, void* d_ws, size_t ws_size,
                              hipStream_t stream) {
    const float* x      = (const float*)d_in[0];
    const float* W_in   = (const float*)d_in[1];
    const float* conv_w = (const float*)d_in[2];
    const float* conv_b = (const float*)d_in[3];
    const float* W_B    = (const float*)d_in[4];
    const float* W_C    = (const float*)d_in[5];
    const float* A      = (const float*)d_in[6];
    const float* D      = (const float*)d_in[7];
    const float* W_out  = (const float*)d_in[8];
    float* out = (float*)d_out;

    char* ws = (char*)d_ws;
    size_t off = 0;
    auto alloc = [&](size_t bytes) { size_t o = off; off += (bytes + 255) & ~(size_t)255; return o; };
    _Float16* xh    = (_Float16*)(ws + alloc((size_t)NROWS * D_MODEL * 2));      // 33.5 MB
    _Float16* WinT  = (_Float16*)(ws + alloc((size_t)4096 * 1024 * 2));          //  8.4 MB
    _Float16* WoutT = (_Float16*)(ws + alloc((size_t)1024 * 2048 * 2));          //  4.2 MB
    _Float16* WBCT  = (_Float16*)(ws + alloc((size_t)32 * 2048 * 2));            //  0.13 MB
    _Float16* xr    = (_Float16*)(ws + alloc((size_t)NROWS * 4096 * 2));         //  134 MB
    _Float16* xc    = (_Float16*)(ws + alloc((size_t)NROWS * D_INNER * 2));      //   67 MB
    float*    BtCt  = (float*)(ws + alloc((size_t)NROWS * 32 * 4));              //    2 MB
    float*    ysbuf = (float*)(ws + alloc((size_t)NROWS * 4));                   //  64 KB

    // 1. conversions
    convert_f32_f16<<<(NROWS * D_MODEL) / (256 * 8), 256, 0, stream>>>(x, xh);
    transpose_to_f16<<<dim3(4096 / 32, 1024 / 32), dim3(32, 8), 0, stream>>>(W_in, WinT, 1024, 4096);
    transpose_to_f16<<<dim3(1024 / 32, 2048 / 32), dim3(32, 8), 0, stream>>>(W_out, WoutT, 2048, 1024);
    convert_wbct<<<(32 * 2048) / 256, 256, 0, stream>>>(W_B, W_C, WBCT);
    // 2. GEMM1: xr = x @ W_in
    gemm_tn<_Float16><<<dim3(4096 / 128, NROWS / 128), 256, 0, stream>>>(xh, WinT, xr, NROWS, 4096, 1024);
    // 3. conv + silu
    conv_silu<<<NROWS, 256, 0, stream>>>(xr, conv_w, conv_b, xc);
    // 4. Bt/Ct projection
    bc_gemm<<<NROWS / 64, 256, 0, stream>>>(xc, WBCT, BtCt);
    // 5. scan
    scan_kernel<<<NBATCH, 256, 0, stream>>>(BtCt, A, ysbuf);
    // 6. y = (ys + xc*D) * silu(res)
    fuse_y<<<NROWS, 256, 0, stream>>>(ysbuf, D, xr, xc);
    // 7. GEMM2: out = y @ W_out
    gemm_tn<float><<<dim3(1024 / 128, NROWS / 128), 256, 0, stream>>>(xc, WoutT, out, NROWS, 1024, 2048);
}

// Round 2
// 530.703 us; speedup vs baseline: 1.1447x; 1.1447x over previous
//
#include <hip/hip_runtime.h>

// ---------------------------------------------------------------------------
// MambaLayer on MI355X (gfx950).
// Pipeline (all f16 MFMA with fp32 accumulate; scan/elementwise in fp32):
//   1. convert x -> f16; transpose-convert W_in, W_out -> N-major f16 (B^T form)
//   2. GEMM1: xr = x @ W_in        (16384x1024 @ 1024x4096), f16 out
//   3. conv(3, depthwise, pad 1) + SiLU -> xc (f16)
//   4. bc_gemm: BtCt = xc @ [W_B|W_C]  (N=32, fp32 out)
//   5. chunk-parallel scan -> ys (fp32, 16384)
//   6. fuse_y: y = (ys + xc*D) * silu(res) -> overwrite xc buffer (f16)
//   7. GEMM2: out = y @ W_out      (16384x2048 @ 2048x1024), fp32 out
//
// R1: gemm_tn: BK 32->64 (halve barrier drains) + XOR-swizzled LDS layout
//     (LDS[r][c ^ (r&7)] 16B chunks) to kill the 8-way fragment-read bank
//     conflicts (SQ_LDS_BANK_CONFLICT was 1.68e7 ~ 13% of cycles).
//     scan: 64 chunks x 64 steps, 1024 thr/block (was 16x256, 256 thr).
// ---------------------------------------------------------------------------

typedef _Float16 half8 __attribute__((ext_vector_type(8)));
typedef float floatx4 __attribute__((ext_vector_type(4)));

#define D_MODEL 1024
#define D_INNER 2048
#define SEQ     4096
#define NBATCH  4
#define NROWS   (NBATCH * SEQ)        // 16384

__device__ __forceinline__ void async16(_Float16* lds, const _Float16* g) {
    // global -> LDS direct copy, 16B per lane; LDS dest = wave-uniform base + lane*16
    __builtin_amdgcn_global_load_lds((const __attribute__((address_space(1))) void*)g,
                                     (__attribute__((address_space(3))) void*)lds, 16, 0, 0);
}

__device__ __forceinline__ float siluf(float x) {
    return x / (1.f + __expf(-x));
}

// --------------------------- conversion kernels ----------------------------

__global__ __launch_bounds__(256) void convert_f32_f16(const float* __restrict__ src,
                                                       _Float16* __restrict__ dst) {
    size_t idx = ((size_t)blockIdx.x * 256 + threadIdx.x) * 8;
    float4 a = *(const float4*)(src + idx);
    float4 b = *(const float4*)(src + idx + 4);
    half8 o = {(_Float16)a.x, (_Float16)a.y, (_Float16)a.z, (_Float16)a.w,
               (_Float16)b.x, (_Float16)b.y, (_Float16)b.z, (_Float16)b.w};
    *(half8*)(dst + idx) = o;
}

// src: K x N fp32 (row-major), dst: N x K f16 (row-major)  [i.e. B^T]
__global__ __launch_bounds__(256) void transpose_to_f16(const float* __restrict__ src,
                                                        _Float16* __restrict__ dst,
                                                        int K, int N) {
    __shared__ float tile[32][33];
    int n0 = blockIdx.x * 32, k0 = blockIdx.y * 32;
    int x = threadIdx.x, y = threadIdx.y;   // 32 x 8
#pragma unroll
    for (int r = 0; r < 32; r += 8)
        tile[y + r][x] = src[(size_t)(k0 + y + r) * N + (n0 + x)];
    __syncthreads();
#pragma unroll
    for (int r = 0; r < 32; r += 8)
        dst[(size_t)(n0 + y + r) * K + (k0 + x)] = (_Float16)tile[x][y + r];
}

// WBCT[n][k], n<16 -> W_B[:,n], n>=16 -> W_C[:,n-16]; shape 32 x 2048 f16
__global__ __launch_bounds__(256) void convert_wbct(const float* __restrict__ WB,
                                                    const float* __restrict__ WC,
                                                    _Float16* __restrict__ WBCT) {
    int idx = blockIdx.x * 256 + threadIdx.x;   // 0 .. 65535
    int n = idx >> 11, k = idx & 2047;
    float v = (n < 16) ? WB[k * 16 + n] : WC[k * 16 + (n - 16)];
    WBCT[idx] = (_Float16)v;
}

// ------------------------------- main GEMM ---------------------------------
// C(MxN) = A(MxK) * B(KxN), with B given as BT (NxK row-major). All f16 in,
// fp32 accumulate. 128x128 block tile, BK=64, 4 waves in 2x2 of 64x64.
// LDS layout is XOR-swizzled in 16B chunks: element chunk c of row r lives at
// LDS[r*64 + (c ^ (r&7))*8]. Staging achieves this by permuting the GLOBAL
// source column per lane (global_load_lds dest is pinned to base+lane*16).
template <typename OutT>
__global__ __launch_bounds__(256) void gemm_tn(const _Float16* __restrict__ A,
                                               const _Float16* __restrict__ BT,
                                               OutT* __restrict__ C,
                                               int M, int N, int K) {
    __shared__ __align__(16) _Float16 As[128 * 64];
    __shared__ __align__(16) _Float16 Bs[128 * 64];
    const int tid = threadIdx.x;
    const int wid = tid >> 6, lane = tid & 63;
    const int row0 = blockIdx.y * 128, col0 = blockIdx.x * 128;
    const int wm = (wid & 1) * 64, wn = (wid >> 1) * 64;

    floatx4 acc[4][4] = {};

    // staging: wave wid owns rows [wid*32, wid*32+32); 4 issues of 8 rows each.
    // issue t: row = wid*32 + t*8 + (lane>>3), global col chunk = (lane&7)^(lane>>3)
    const int sr = lane >> 3;                  // 0..7
    const int sc = ((lane & 7) ^ sr) * 8;      // swizzled source col (elements)
    const size_t aBase = (size_t)(row0 + wid * 32 + sr) * K + sc;
    const size_t bBase = (size_t)(col0 + wid * 32 + sr) * K + sc;
    _Float16* ldsA = As + wid * 2048;          // 32 rows * 64 elems
    _Float16* ldsB = Bs + wid * 2048;

    const int fr = lane & 15, q = lane >> 4;
    const int frq = fr & 7;

    for (int k0 = 0; k0 < K; k0 += 64) {
        __syncthreads();
#pragma unroll
        for (int t = 0; t < 4; t++) {
            async16(ldsA + t * 512, A + aBase + (size_t)(t * 8) * K + k0);
            async16(ldsB + t * 512, BT + bBase + (size_t)(t * 8) * K + k0);
        }
        __syncthreads();
#pragma unroll
        for (int kk = 0; kk < 2; kk++) {
            const int sw = (((kk << 2) + q) ^ frq) * 8;   // swizzled chunk offset
            half8 af[4], bf[4];
#pragma unroll
            for (int i = 0; i < 4; i++) {
                af[i] = *(const half8*)(As + (wm + i * 16 + fr) * 64 + sw);
                bf[i] = *(const half8*)(Bs + (wn + i * 16 + fr) * 64 + sw);
            }
#pragma unroll
            for (int i = 0; i < 4; i++)
#pragma unroll
                for (int j = 0; j < 4; j++)
                    acc[i][j] = __builtin_amdgcn_mfma_f32_16x16x32_f16(af[i], bf[j], acc[i][j], 0, 0, 0);
        }
    }

    // C/D layout: col = lane&15, row = (lane>>4)*4 + reg   [measured m89/m91]
    const int er = (lane >> 4) * 4, ec = lane & 15;
#pragma unroll
    for (int i = 0; i < 4; i++)
#pragma unroll
        for (int j = 0; j < 4; j++)
#pragma unroll
            for (int r = 0; r < 4; r++) {
                int row = row0 + wm + i * 16 + er + r;
                int col = col0 + wn + j * 16 + ec;
                C[(size_t)row * N + col] = (OutT)acc[i][j][r];
            }
}

// ------------------------- skinny GEMM for Bt/Ct ---------------------------
// BtCt(M x 32) = xc(M x 2048) @ [W_B | W_C]; BT = WBCT (32 x 2048 f16).
__global__ __launch_bounds__(256) void bc_gemm(const _Float16* __restrict__ A,
                                               const _Float16* __restrict__ BT,
                                               float* __restrict__ C) {
    const int K = D_INNER;
    __shared__ __align__(16) _Float16 As[64 * 64];
    __shared__ __align__(16) _Float16 Bs[32 * 64];
    const int tid = threadIdx.x, wid = tid >> 6, lane = tid & 63;
    const int row0 = blockIdx.x * 64;
    floatx4 acc[2] = {};

    const int srow = lane >> 3;            // 0..7
    const int scol = (lane & 7) * 8;       // 0..56
    const size_t aOff0 = (size_t)(row0 + wid * 16 + srow) * K + scol;
    const size_t aOff1 = aOff0 + (size_t)8 * K;
    const size_t bOff  = (size_t)(wid * 8 + srow) * K + scol;
    _Float16* ldsA = As + wid * 1024;
    _Float16* ldsB = Bs + wid * 512;
    const int fr = lane & 15, fc = (lane >> 4) * 8;

    for (int k0 = 0; k0 < K; k0 += 64) {
        __syncthreads();
        async16(ldsA,       A + aOff0 + k0);
        async16(ldsA + 512, A + aOff1 + k0);
        async16(ldsB,       BT + bOff + k0);
        __syncthreads();
#pragma unroll
        for (int s = 0; s < 2; s++) {
            half8 af = *(const half8*)(As + (wid * 16 + fr) * 64 + s * 32 + fc);
#pragma unroll
            for (int nj = 0; nj < 2; nj++) {
                half8 bf = *(const half8*)(Bs + (nj * 16 + fr) * 64 + s * 32 + fc);
                acc[nj] = __builtin_amdgcn_mfma_f32_16x16x32_f16(af, bf, acc[nj], 0, 0, 0);
            }
        }
    }
    const int er = (lane >> 4) * 4, ec = lane & 15;
#pragma unroll
    for (int nj = 0; nj < 2; nj++)
#pragma unroll
        for (int r = 0; r < 4; r++)
            C[(size_t)(row0 + wid * 16 + er + r) * 32 + nj * 16 + ec] = acc[nj][r];
}

// ----------------------------- conv + silu ---------------------------------
__global__ __launch_bounds__(256) void conv_silu(const _Float16* __restrict__ xr,
                                                 const float* __restrict__ cw,
                                                 const float* __restrict__ cb,
                                                 _Float16* __restrict__ xc) {
    int row = blockIdx.x;           // b*SEQ + l
    int l = row & (SEQ - 1);
    int i = threadIdx.x * 8;
    const _Float16* cur = xr + (size_t)row * 4096 + i;   // x_main = cols [0,2048)
    half8 c8 = *(const half8*)cur;
    half8 p8 = {}, n8 = {};
    if (l > 0)       p8 = *(const half8*)(cur - 4096);
    if (l < SEQ - 1) n8 = *(const half8*)(cur + 4096);
    half8 o;
#pragma unroll
    for (int j = 0; j < 8; j++) {
        int ii = i + j;
        float a = (float)p8[j] * cw[ii * 3] + (float)c8[j] * cw[ii * 3 + 1] +
                  (float)n8[j] * cw[ii * 3 + 2] + cb[ii];
        o[j] = (_Float16)siluf(a);
    }
    *(half8*)(xc + (size_t)row * D_INNER + i) = o;
}

// -------------------------------- scan -------------------------------------
// state[s] = state[s]*decay[s] + Bt[l,s];  ys[l] = sum_s state[s]*Ct[l,s]
// 3-phase chunked scan: 64 chunks x 64 steps per batch; thread = (chunk, s).
__global__ __launch_bounds__(1024) void scan_kernel(const float* __restrict__ BtCt,
                                                    const float* __restrict__ A,
                                                    float* __restrict__ ys) {
    const int b = blockIdx.x, t = threadIdx.x;
    const int c = t >> 4, s = t & 15;          // c: 0..63, s: 0..15
    const float decay = __expf(-log1pf(__expf(A[s])));
    const size_t base = (size_t)b * SEQ * 32;
    const int l0 = c * 64;

    float st = 0.f;
    for (int j = 0; j < 64; j++)
        st = st * decay + BtCt[base + (size_t)(l0 + j) * 32 + s];

    __shared__ float fin[64][16];
    __shared__ float carry[64][16];
    fin[c][s] = st;
    __syncthreads();
    if (t < 16) {                       // c==0, s==t
        float d64 = decay;
#pragma unroll
        for (int k = 0; k < 6; k++) d64 *= d64;   // decay^64
        float cy = 0.f;
        for (int cc = 0; cc < 64; cc++) {
            carry[cc][s] = cy;
            cy = cy * d64 + fin[cc][s];
        }
    }
    __syncthreads();

    st = carry[c][s];
    for (int j = 0; j < 64; j++) {
        size_t r = base + (size_t)(l0 + j) * 32;
        st = st * decay + BtCt[r + s];
        float y = st * BtCt[r + 16 + s];
        y += __shfl_xor(y, 1, 16);
        y += __shfl_xor(y, 2, 16);
        y += __shfl_xor(y, 4, 16);
        y += __shfl_xor(y, 8, 16);
        if (s == 0) ys[b * SEQ + l0 + j] = y;
    }
}

// ------------------------- fused elementwise y -----------------------------
// y = (ys + xc*D) * silu(res); overwrite xc in place (read-once elementwise).
__global__ __launch_bounds__(256) void fuse_y(const float* __restrict__ ys,
                                              const float* __restrict__ D,
                                              const _Float16* __restrict__ xr,
                                              _Float16* __restrict__ xc) {
    int row = blockIdx.x;
    int i = threadIdx.x * 8;
    float yv = ys[row];
    half8 x8 = *(const half8*)(xc + (size_t)row * D_INNER + i);
    half8 r8 = *(const half8*)(xr + (size_t)row * 4096 + 2048 + i);
    half8 o;
#pragma unroll
    for (int j = 0; j < 8; j++) {
        float y = yv + (float)x8[j] * D[i + j];
        o[j] = (_Float16)(y * siluf((float)r8[j]));
    }
    *(half8*)(xc + (size_t)row * D_INNER + i) = o;
}

// ------------------------------- launcher ----------------------------------
extern "C" void kernel_launch(void* const* d_in, const int* in_sizes, int n_in,
                              void* d_out, int out_size, void* d_ws, size_t ws_size,
                              hipStream_t stream) {
    const float* x      = (const float*)d_in[0];
    const float* W_in   = (const float*)d_in[1];
    const float* conv_w = (const float*)d_in[2];
    const float* conv_b = (const float*)d_in[3];
    const float* W_B    = (const float*)d_in[4];
    const float* W_C    = (const float*)d_in[5];
    const float* A      = (const float*)d_in[6];
    const float* D      = (const float*)d_in[7];
    const float* W_out  = (const float*)d_in[8];
    float* out = (float*)d_out;

    char* ws = (char*)d_ws;
    size_t off = 0;
    auto alloc = [&](size_t bytes) { size_t o = off; off += (bytes + 255) & ~(size_t)255; return o; };
    _Float16* xh    = (_Float16*)(ws + alloc((size_t)NROWS * D_MODEL * 2));      // 33.5 MB
    _Float16* WinT  = (_Float16*)(ws + alloc((size_t)4096 * 1024 * 2));          //  8.4 MB
    _Float16* WoutT = (_Float16*)(ws + alloc((size_t)1024 * 2048 * 2));          //  4.2 MB
    _Float16* WBCT  = (_Float16*)(ws + alloc((size_t)32 * 2048 * 2));            //  0.13 MB
    _Float16* xr    = (_Float16*)(ws + alloc((size_t)NROWS * 4096 * 2));         //  134 MB
    _Float16* xc    = (_Float16*)(ws + alloc((size_t)NROWS * D_INNER * 2));      //   67 MB
    float*    BtCt  = (float*)(ws + alloc((size_t)NROWS * 32 * 4));              //    2 MB
    float*    ysbuf = (float*)(ws + alloc((size_t)NROWS * 4));                   //  64 KB

    // 1. conversions
    convert_f32_f16<<<(NROWS * D_MODEL) / (256 * 8), 256, 0, stream>>>(x, xh);
    transpose_to_f16<<<dim3(4096 / 32, 1024 / 32), dim3(32, 8), 0, stream>>>(W_in, WinT, 1024, 4096);
    transpose_to_f16<<<dim3(1024 / 32, 2048 / 32), dim3(32, 8), 0, stream>>>(W_out, WoutT, 2048, 1024);
    convert_wbct<<<(32 * 2048) / 256, 256, 0, stream>>>(W_B, W_C, WBCT);
    // 2. GEMM1: xr = x @ W_in
    gemm_tn<_Float16><<<dim3(4096 / 128, NROWS / 128), 256, 0, stream>>>(xh, WinT, xr, NROWS, 4096, 1024);
    // 3. conv + silu
    conv_silu<<<NROWS, 256, 0, stream>>>(xr, conv_w, conv_b, xc);
    // 4. Bt/Ct projection
    bc_gemm<<<NROWS / 64, 256, 0, stream>>>(xc, WBCT, BtCt);
    // 5. scan
    scan_kernel<<<NBATCH, 1024, 0, stream>>>(BtCt, A, ysbuf);
    // 6. y = (ys + xc*D) * silu(res)
    fuse_y<<<NROWS, 256, 0, stream>>>(ysbuf, D, xr, xc);
    // 7. GEMM2: out = y @ W_out
    gemm_tn<float><<<dim3(1024 / 128, NROWS / 128), 256, 0, stream>>>(xc, WoutT, out, NROWS, 1024, 2048);
}

// Round 3
// 518.299 us; speedup vs baseline: 1.1721x; 1.0239x over previous
//
#include <hip/hip_runtime.h>

// ---------------------------------------------------------------------------
// MambaLayer on MI355X (gfx950).
// Pipeline (all f16 MFMA with fp32 accumulate; scan/elementwise in fp32):
//   1. convert x -> f16; transpose-convert W_in, W_out -> N-major f16 (B^T form)
//   2. GEMM1: xr = x @ W_in        (16384x1024 @ 1024x4096), f16 out
//   3. conv(3, depthwise, pad 1) + SiLU -> xc (f16)
//   4. bc_gemm: BtCt = xc @ [W_B|W_C]  (N=32, fp32 out)
//   5. scan phase1/2: per-chunk states + carry propagation (wide grids)
//   6. scan phase3 fused with y-fuse: replay chunk scan -> ys in LDS, then
//      y = (ys + xc*D) * silu(res) -> overwrite xc (f16)
//   7. GEMM2: out = y @ W_out      (16384x2048 @ 2048x1024), fp32 out
//
// R1: gemm_tn: BK 32->64 + XOR-swizzled LDS (conflicts 1.68e7 -> 0; 202->164us)
// R2: scan restructured: was 4 blocks (4 CUs!) + separate fuse_y pass.
//     Now: p1 = 64 blocks x 256 (1024 chunks x 16 states, chunk len 16),
//     p2 = 1 block carry scan, p3 = 1024 blocks fusing scan replay + y-fuse.
// ---------------------------------------------------------------------------

typedef _Float16 half8 __attribute__((ext_vector_type(8)));
typedef float floatx4 __attribute__((ext_vector_type(4)));

#define D_MODEL 1024
#define D_INNER 2048
#define SEQ     4096
#define NBATCH  4
#define NROWS   (NBATCH * SEQ)        // 16384
#define CHUNK   16
#define NCHUNK  (SEQ / CHUNK)         // 256 chunks per batch
#define NTASK   (NBATCH * NCHUNK)     // 1024 chunk-tasks

__device__ __forceinline__ void async16(_Float16* lds, const _Float16* g) {
    // global -> LDS direct copy, 16B per lane; LDS dest = wave-uniform base + lane*16
    __builtin_amdgcn_global_load_lds((const __attribute__((address_space(1))) void*)g,
                                     (__attribute__((address_space(3))) void*)lds, 16, 0, 0);
}

__device__ __forceinline__ float siluf(float x) {
    return x / (1.f + __expf(-x));
}

__device__ __forceinline__ float decay_of(const float* A, int s) {
    return __expf(-log1pf(__expf(A[s])));   // exp(-softplus(A[s]))
}

// --------------------------- conversion kernels ----------------------------

__global__ __launch_bounds__(256) void convert_f32_f16(const float* __restrict__ src,
                                                       _Float16* __restrict__ dst) {
    size_t idx = ((size_t)blockIdx.x * 256 + threadIdx.x) * 8;
    float4 a = *(const float4*)(src + idx);
    float4 b = *(const float4*)(src + idx + 4);
    half8 o = {(_Float16)a.x, (_Float16)a.y, (_Float16)a.z, (_Float16)a.w,
               (_Float16)b.x, (_Float16)b.y, (_Float16)b.z, (_Float16)b.w};
    *(half8*)(dst + idx) = o;
}

// src: K x N fp32 (row-major), dst: N x K f16 (row-major)  [i.e. B^T]
__global__ __launch_bounds__(256) void transpose_to_f16(const float* __restrict__ src,
                                                        _Float16* __restrict__ dst,
                                                        int K, int N) {
    __shared__ float tile[32][33];
    int n0 = blockIdx.x * 32, k0 = blockIdx.y * 32;
    int x = threadIdx.x, y = threadIdx.y;   // 32 x 8
#pragma unroll
    for (int r = 0; r < 32; r += 8)
        tile[y + r][x] = src[(size_t)(k0 + y + r) * N + (n0 + x)];
    __syncthreads();
#pragma unroll
    for (int r = 0; r < 32; r += 8)
        dst[(size_t)(n0 + y + r) * K + (k0 + x)] = (_Float16)tile[x][y + r];
}

// WBCT[n][k], n<16 -> W_B[:,n], n>=16 -> W_C[:,n-16]; shape 32 x 2048 f16
__global__ __launch_bounds__(256) void convert_wbct(const float* __restrict__ WB,
                                                    const float* __restrict__ WC,
                                                    _Float16* __restrict__ WBCT) {
    int idx = blockIdx.x * 256 + threadIdx.x;   // 0 .. 65535
    int n = idx >> 11, k = idx & 2047;
    float v = (n < 16) ? WB[k * 16 + n] : WC[k * 16 + (n - 16)];
    WBCT[idx] = (_Float16)v;
}

// ------------------------------- main GEMM ---------------------------------
// C(MxN) = A(MxK) * B(KxN), with B given as BT (NxK row-major). All f16 in,
// fp32 accumulate. 128x128 block tile, BK=64, 4 waves in 2x2 of 64x64.
// LDS layout is XOR-swizzled in 16B chunks: element chunk c of row r lives at
// LDS[r*64 + (c ^ (r&7))*8]. Staging achieves this by permuting the GLOBAL
// source column per lane (global_load_lds dest is pinned to base+lane*16).
template <typename OutT>
__global__ __launch_bounds__(256) void gemm_tn(const _Float16* __restrict__ A,
                                               const _Float16* __restrict__ BT,
                                               OutT* __restrict__ C,
                                               int M, int N, int K) {
    __shared__ __align__(16) _Float16 As[128 * 64];
    __shared__ __align__(16) _Float16 Bs[128 * 64];
    const int tid = threadIdx.x;
    const int wid = tid >> 6, lane = tid & 63;
    const int row0 = blockIdx.y * 128, col0 = blockIdx.x * 128;
    const int wm = (wid & 1) * 64, wn = (wid >> 1) * 64;

    floatx4 acc[4][4] = {};

    const int sr = lane >> 3;                  // 0..7
    const int sc = ((lane & 7) ^ sr) * 8;      // swizzled source col (elements)
    const size_t aBase = (size_t)(row0 + wid * 32 + sr) * K + sc;
    const size_t bBase = (size_t)(col0 + wid * 32 + sr) * K + sc;
    _Float16* ldsA = As + wid * 2048;          // 32 rows * 64 elems
    _Float16* ldsB = Bs + wid * 2048;

    const int fr = lane & 15, q = lane >> 4;
    const int frq = fr & 7;

    for (int k0 = 0; k0 < K; k0 += 64) {
        __syncthreads();
#pragma unroll
        for (int t = 0; t < 4; t++) {
            async16(ldsA + t * 512, A + aBase + (size_t)(t * 8) * K + k0);
            async16(ldsB + t * 512, BT + bBase + (size_t)(t * 8) * K + k0);
        }
        __syncthreads();
#pragma unroll
        for (int kk = 0; kk < 2; kk++) {
            const int sw = (((kk << 2) + q) ^ frq) * 8;   // swizzled chunk offset
            half8 af[4], bf[4];
#pragma unroll
            for (int i = 0; i < 4; i++) {
                af[i] = *(const half8*)(As + (wm + i * 16 + fr) * 64 + sw);
                bf[i] = *(const half8*)(Bs + (wn + i * 16 + fr) * 64 + sw);
            }
#pragma unroll
            for (int i = 0; i < 4; i++)
#pragma unroll
                for (int j = 0; j < 4; j++)
                    acc[i][j] = __builtin_amdgcn_mfma_f32_16x16x32_f16(af[i], bf[j], acc[i][j], 0, 0, 0);
        }
    }

    // C/D layout: col = lane&15, row = (lane>>4)*4 + reg   [measured m89/m91]
    const int er = (lane >> 4) * 4, ec = lane & 15;
#pragma unroll
    for (int i = 0; i < 4; i++)
#pragma unroll
        for (int j = 0; j < 4; j++)
#pragma unroll
            for (int r = 0; r < 4; r++) {
                int row = row0 + wm + i * 16 + er + r;
                int col = col0 + wn + j * 16 + ec;
                C[(size_t)row * N + col] = (OutT)acc[i][j][r];
            }
}

// ------------------------- skinny GEMM for Bt/Ct ---------------------------
// BtCt(M x 32) = xc(M x 2048) @ [W_B | W_C]; BT = WBCT (32 x 2048 f16).
__global__ __launch_bounds__(256) void bc_gemm(const _Float16* __restrict__ A,
                                               const _Float16* __restrict__ BT,
                                               float* __restrict__ C) {
    const int K = D_INNER;
    __shared__ __align__(16) _Float16 As[64 * 64];
    __shared__ __align__(16) _Float16 Bs[32 * 64];
    const int tid = threadIdx.x, wid = tid >> 6, lane = tid & 63;
    const int row0 = blockIdx.x * 64;
    floatx4 acc[2] = {};

    const int srow = lane >> 3;            // 0..7
    const int scol = (lane & 7) * 8;       // 0..56
    const size_t aOff0 = (size_t)(row0 + wid * 16 + srow) * K + scol;
    const size_t aOff1 = aOff0 + (size_t)8 * K;
    const size_t bOff  = (size_t)(wid * 8 + srow) * K + scol;
    _Float16* ldsA = As + wid * 1024;
    _Float16* ldsB = Bs + wid * 512;
    const int fr = lane & 15, fc = (lane >> 4) * 8;

    for (int k0 = 0; k0 < K; k0 += 64) {
        __syncthreads();
        async16(ldsA,       A + aOff0 + k0);
        async16(ldsA + 512, A + aOff1 + k0);
        async16(ldsB,       BT + bOff + k0);
        __syncthreads();
#pragma unroll
        for (int s = 0; s < 2; s++) {
            half8 af = *(const half8*)(As + (wid * 16 + fr) * 64 + s * 32 + fc);
#pragma unroll
            for (int nj = 0; nj < 2; nj++) {
                half8 bf = *(const half8*)(Bs + (nj * 16 + fr) * 64 + s * 32 + fc);
                acc[nj] = __builtin_amdgcn_mfma_f32_16x16x32_f16(af, bf, acc[nj], 0, 0, 0);
            }
        }
    }
    const int er = (lane >> 4) * 4, ec = lane & 15;
#pragma unroll
    for (int nj = 0; nj < 2; nj++)
#pragma unroll
        for (int r = 0; r < 4; r++)
            C[(size_t)(row0 + wid * 16 + er + r) * 32 + nj * 16 + ec] = acc[nj][r];
}

// ----------------------------- conv + silu ---------------------------------
__global__ __launch_bounds__(256) void conv_silu(const _Float16* __restrict__ xr,
                                                 const float* __restrict__ cw,
                                                 const float* __restrict__ cb,
                                                 _Float16* __restrict__ xc) {
    int row = blockIdx.x;           // b*SEQ + l
    int l = row & (SEQ - 1);
    int i = threadIdx.x * 8;
    const _Float16* cur = xr + (size_t)row * 4096 + i;   // x_main = cols [0,2048)
    half8 c8 = *(const half8*)cur;
    half8 p8 = {}, n8 = {};
    if (l > 0)       p8 = *(const half8*)(cur - 4096);
    if (l < SEQ - 1) n8 = *(const half8*)(cur + 4096);
    half8 o;
#pragma unroll
    for (int j = 0; j < 8; j++) {
        int ii = i + j;
        float a = (float)p8[j] * cw[ii * 3] + (float)c8[j] * cw[ii * 3 + 1] +
                  (float)n8[j] * cw[ii * 3 + 2] + cb[ii];
        o[j] = (_Float16)siluf(a);
    }
    *(half8*)(xc + (size_t)row * D_INNER + i) = o;
}

// -------------------------------- scan -------------------------------------
// state[s] = state[s]*decay[s] + Bt[l,s];  ys[l] = sum_s state[s]*Ct[l,s]
// Chunked 3-phase scan, chunk length 16; NTASK=1024 chunk-tasks x 16 states.

// phase 1: per-chunk final states. 64 blocks x 256 threads.
__global__ __launch_bounds__(256) void scan_p1(const float* __restrict__ BtCt,
                                               const float* __restrict__ A,
                                               float* __restrict__ fin) {
    int g = blockIdx.x * 256 + threadIdx.x;     // 0..16383
    int task = g >> 4, s = g & 15;
    int b = task >> 8, c = task & (NCHUNK - 1);
    const float decay = decay_of(A, s);
    size_t r = ((size_t)b * SEQ + c * CHUNK) * 32;
    float st = 0.f;
#pragma unroll
    for (int j = 0; j < CHUNK; j++)
        st = st * decay + BtCt[r + (size_t)j * 32 + s];
    fin[task * 16 + s] = st;
}

// phase 2: carry propagation across chunks. 1 block x 64 threads (b,s).
__global__ __launch_bounds__(64) void scan_p2(const float* __restrict__ fin,
                                              const float* __restrict__ A,
                                              float* __restrict__ carry) {
    int t = threadIdx.x;
    int b = t >> 4, s = t & 15;
    float decay = decay_of(A, s);
    float d16 = decay;
#pragma unroll
    for (int k = 0; k < 4; k++) d16 *= d16;     // decay^16
    float cy = 0.f;
    for (int c = 0; c < NCHUNK; c++) {
        int idx = ((b * NCHUNK) + c) * 16 + s;
        carry[idx] = cy;
        cy = cy * d16 + fin[idx];
    }
}

// phase 3 + y-fuse: replay chunk scan (lanes 0..15) -> ys in LDS, then all
// 256 threads compute y = (ys + xc*D) * silu(res), overwriting xc (f16).
// 1024 blocks x 256 threads; block = chunk-task (16 rows).
__global__ __launch_bounds__(256) void scan_p3_fuse(const float* __restrict__ BtCt,
                                                    const float* __restrict__ A,
                                                    const float* __restrict__ carry,
                                                    const float* __restrict__ D,
                                                    const _Float16* __restrict__ xr,
                                                    _Float16* __restrict__ xc) {
    __shared__ float ysl[CHUNK];
    const int task = blockIdx.x;
    const int b = task >> 8, c = task & (NCHUNK - 1);
    const int row0 = b * SEQ + c * CHUNK;
    const int tid = threadIdx.x;

    if (tid < 16) {
        const int s = tid;
        const float decay = decay_of(A, s);
        float st = carry[task * 16 + s];
        size_t r = (size_t)row0 * 32;
#pragma unroll
        for (int j = 0; j < CHUNK; j++) {
            st = st * decay + BtCt[r + s];
            float y = st * BtCt[r + 16 + s];
            y += __shfl_xor(y, 1, 16);
            y += __shfl_xor(y, 2, 16);
            y += __shfl_xor(y, 4, 16);
            y += __shfl_xor(y, 8, 16);
            if (s == 0) ysl[j] = y;
            r += 32;
        }
    }
    __syncthreads();

#pragma unroll
    for (int it = 0; it < 16; it++) {
        int chunk = it * 256 + tid;            // 0..4095 (16 rows x 256 col-chunks)
        int rl = chunk >> 8;                   // row within chunk
        int colb = (chunk & 255) * 8;          // col offset (elements)
        size_t row = (size_t)(row0 + rl);
        float yv = ysl[rl];
        half8 x8 = *(const half8*)(xc + row * D_INNER + colb);
        half8 r8 = *(const half8*)(xr + row * 4096 + 2048 + colb);
        float4 d0 = *(const float4*)(D + colb);
        float4 d1 = *(const float4*)(D + colb + 4);
        half8 o;
        float dd[8] = {d0.x, d0.y, d0.z, d0.w, d1.x, d1.y, d1.z, d1.w};
#pragma unroll
        for (int j = 0; j < 8; j++) {
            float y = yv + (float)x8[j] * dd[j];
            o[j] = (_Float16)(y * siluf((float)r8[j]));
        }
        *(half8*)(xc + row * D_INNER + colb) = o;
    }
}

// ------------------------------- launcher ----------------------------------
extern "C" void kernel_launch(void* const* d_in, const int* in_sizes, int n_in,
                              void* d_out, int out_size, void* d_ws, size_t ws_size,
                              hipStream_t stream) {
    const float* x      = (const float*)d_in[0];
    const float* W_in   = (const float*)d_in[1];
    const float* conv_w = (const float*)d_in[2];
    const float* conv_b = (const float*)d_in[3];
    const float* W_B    = (const float*)d_in[4];
    const float* W_C    = (const float*)d_in[5];
    const float* A      = (const float*)d_in[6];
    const float* D      = (const float*)d_in[7];
    const float* W_out  = (const float*)d_in[8];
    float* out = (float*)d_out;

    char* ws = (char*)d_ws;
    size_t off = 0;
    auto alloc = [&](size_t bytes) { size_t o = off; off += (bytes + 255) & ~(size_t)255; return o; };
    _Float16* xh    = (_Float16*)(ws + alloc((size_t)NROWS * D_MODEL * 2));      // 33.5 MB
    _Float16* WinT  = (_Float16*)(ws + alloc((size_t)4096 * 1024 * 2));          //  8.4 MB
    _Float16* WoutT = (_Float16*)(ws + alloc((size_t)1024 * 2048 * 2));          //  4.2 MB
    _Float16* WBCT  = (_Float16*)(ws + alloc((size_t)32 * 2048 * 2));            //  0.13 MB
    _Float16* xr    = (_Float16*)(ws + alloc((size_t)NROWS * 4096 * 2));         //  134 MB
    _Float16* xc    = (_Float16*)(ws + alloc((size_t)NROWS * D_INNER * 2));      //   67 MB
    float*    BtCt  = (float*)(ws + alloc((size_t)NROWS * 32 * 4));              //    2 MB
    float*    fin   = (float*)(ws + alloc((size_t)NTASK * 16 * 4));              //  64 KB
    float*    carry = (float*)(ws + alloc((size_t)NTASK * 16 * 4));              //  64 KB

    // 1. conversions
    convert_f32_f16<<<(NROWS * D_MODEL) / (256 * 8), 256, 0, stream>>>(x, xh);
    transpose_to_f16<<<dim3(4096 / 32, 1024 / 32), dim3(32, 8), 0, stream>>>(W_in, WinT, 1024, 4096);
    transpose_to_f16<<<dim3(1024 / 32, 2048 / 32), dim3(32, 8), 0, stream>>>(W_out, WoutT, 2048, 1024);
    convert_wbct<<<(32 * 2048) / 256, 256, 0, stream>>>(W_B, W_C, WBCT);
    // 2. GEMM1: xr = x @ W_in
    gemm_tn<_Float16><<<dim3(4096 / 128, NROWS / 128), 256, 0, stream>>>(xh, WinT, xr, NROWS, 4096, 1024);
    // 3. conv + silu
    conv_silu<<<NROWS, 256, 0, stream>>>(xr, conv_w, conv_b, xc);
    // 4. Bt/Ct projection
    bc_gemm<<<NROWS / 64, 256, 0, stream>>>(xc, WBCT, BtCt);
    // 5. scan phases 1-2
    scan_p1<<<NTASK * 16 / 256, 256, 0, stream>>>(BtCt, A, fin);
    scan_p2<<<1, 64, 0, stream>>>(fin, A, carry);
    // 6. scan phase 3 + y-fuse
    scan_p3_fuse<<<NTASK, 256, 0, stream>>>(BtCt, A, carry, D, xr, xc);
    // 7. GEMM2: out = y @ W_out
    gemm_tn<float><<<dim3(1024 / 128, NROWS / 128), 256, 0, stream>>>(xc, WoutT, out, NROWS, 1024, 2048);
}